// Round 1
// baseline (40.827 us; speedup 1.0000x reference)
//
#include <hip/hip_runtime.h>

// BinaryTreeShConv on MI355X (gfx950).
// out[b,v,i] = relu(bias[i] + sum_{p,c,rn} W[i,c,rn] * K[b,v,p,rn] * sig[b, idx[b,v,p], c])
// B=8 V=4096 P=32 C=32 RN=32 OUT=32, CRN=1024.
//
// Stage A (per bv, one wave): T(32c x 32rn) = S^T(32c x 32p) @ K(32p x 32rn)
//   via 2x mfma_f32_32x32x16_bf16. T -> LDS bf16, padded stride 1032.
// Stage B (per block of 16 bv): Out(16bv x 32i) = T(16bv x 1024) @ W^T
//   via mfma_f32_16x16x32_bf16, k-split over 4 waves, LDS reduce.
// W pre-converted once per call to fragment-ordered bf16 in d_ws (64 KB).

typedef __attribute__((ext_vector_type(8))) short bf16x8;
typedef __attribute__((ext_vector_type(16))) float f32x16;
typedef __attribute__((ext_vector_type(4))) float f32x4;

__device__ __forceinline__ unsigned short f2bf(float f) {
    union { float f; unsigned int u; } x;
    x.f = f;
    unsigned int u = x.u;
    return (unsigned short)((u + 0x7fffu + ((u >> 16) & 1u)) >> 16);  // RNE
}

// Wf[pair=2s+t][lane][j] = bf16(W[i=16t+(lane&15)][crn=32s+8*(lane>>4)+j])
__global__ __launch_bounds__(256) void prep_w_kernel(
        const float* __restrict__ W, unsigned short* __restrict__ Wf) {
    int tid = blockIdx.x * 256 + threadIdx.x;   // 0 .. 32767
    int j = tid & 7;
    int l = (tid >> 3) & 63;
    int pair = tid >> 9;                        // s*2 + t
    int s = pair >> 1;
    int t = pair & 1;
    int i = 16 * t + (l & 15);
    int crn = 32 * s + 8 * (l >> 4) + j;
    Wf[tid] = f2bf(W[i * 1024 + crn]);
}

__global__ __launch_bounds__(256) void fused_kernel(
        const float* __restrict__ sig, const int* __restrict__ pidx,
        const float* __restrict__ ck, const unsigned short* __restrict__ Wf,
        const float* __restrict__ bias, float* __restrict__ out) {
    __shared__ __align__(16) unsigned short T_lds[16 * 1032];  // 33 KB, pad 8 bf16/row
    const int tid = threadIdx.x;
    const int l = tid & 63;
    const int w = tid >> 6;          // wave 0..3
    const int m0 = blockIdx.x * 16;  // first bv of this block (same b for all 16)
    const int b = m0 >> 12;
    const int cc = l & 31;           // stage-A: A-row (c) and B-col (rn)
    const int g = l >> 5;
    const float* sgb = sig + (size_t)b * (4096 * 32);

    // ---- Stage A: wave w computes T for bv_local = 4w .. 4w+3 ----
    for (int q = 0; q < 4; ++q) {
        const int bvl = w * 4 + q;
        const int m = m0 + bvl;
        const int* idxp = pidx + (size_t)m * 32;
        const float* kt = ck + (size_t)m * 1024;   // K tile [32p][32rn] f32
        f32x16 acc = {};
        #pragma unroll
        for (int half = 0; half < 2; ++half) {
            bf16x8 af, bfr;
            #pragma unroll
            for (int j = 0; j < 8; ++j) {
                const int p = half * 16 + 8 * g + j;     // k index (consistent A/B)
                const int row = idxp[p];
                af[j]  = (short)f2bf(sgb[row * 32 + cc]);  // S^T[c][p]
                bfr[j] = (short)f2bf(kt[p * 32 + cc]);     // K[p][rn]
            }
            acc = __builtin_amdgcn_mfma_f32_32x32x16_bf16(af, bfr, acc, 0, 0, 0);
        }
        // D map (verified): col=l&31, row=(r&3)+8*(r>>2)+4*(l>>5)
        unsigned short* trow = T_lds + bvl * 1032;
        #pragma unroll
        for (int r = 0; r < 16; ++r) {
            const int ct = (r & 3) + 8 * (r >> 2) + 4 * g;
            trow[ct * 32 + cc] = f2bf(acc[r]);   // T[c][rn] as bf16
        }
    }
    __syncthreads();

    // ---- Stage B: wave w handles k-steps s = 8w..8w+7, both i-tiles ----
    f32x4 acc0 = {}, acc1 = {};
    const int lg = l >> 4;
    const int ln = l & 15;
    #pragma unroll
    for (int si = 0; si < 8; ++si) {
        const int s = 8 * w + si;
        // A-frag: T[bv=ln][crn = 32s + 8*lg + j]  (16B aligned: 1032*2 = 16*129)
        const bf16x8 af = *(const bf16x8*)(T_lds + ln * 1032 + s * 32 + 8 * lg);
        const bf16x8* wrow = (const bf16x8*)(Wf + (size_t)(s * 2) * 512);
        const bf16x8 b0 = wrow[l];        // pair 2s+0, coalesced 16B/lane
        const bf16x8 b1 = wrow[64 + l];   // pair 2s+1
        acc0 = __builtin_amdgcn_mfma_f32_16x16x32_bf16(af, b0, acc0, 0, 0, 0);
        acc1 = __builtin_amdgcn_mfma_f32_16x16x32_bf16(af, b1, acc1, 0, 0, 0);
    }
    __syncthreads();                      // all T reads done; reuse LDS as f32 buf

    float* red = (float*)T_lds;           // 4 waves * 2 tiles * 256 f32 = 8 KB
    {
        f32x4* rp = (f32x4*)(red + w * 512);
        rp[l]      = acc0;                // [w][t=0][l][r]
        rp[64 + l] = acc1;                // [w][t=1][l][r]
    }
    __syncthreads();

    // 512 outputs: o = t*256 + l*4 + r ; D map: row(bv)=(l>>4)*4+r, col(i)=16t+(l&15)
    #pragma unroll
    for (int o0 = 0; o0 < 2; ++o0) {
        const int o = o0 * 256 + tid;
        float sum = red[o] + red[512 + o] + red[1024 + o] + red[1536 + o];
        const int t  = o >> 8;
        const int ll = (o >> 2) & 63;
        const int r  = o & 3;
        const int bv = ((ll >> 4) << 2) + r;
        const int i  = 16 * t + (ll & 15);
        sum += bias[i];
        out[(size_t)(m0 + bv) * 32 + i] = sum > 0.f ? sum : 0.f;
    }
}

extern "C" void kernel_launch(void* const* d_in, const int* in_sizes, int n_in,
                              void* d_out, int out_size, void* d_ws, size_t ws_size,
                              hipStream_t stream) {
    const float* sig  = (const float*)d_in[0];
    const int*   pidx = (const int*)d_in[1];
    const float* ck   = (const float*)d_in[2];
    const float* W    = (const float*)d_in[3];
    const float* bias = (const float*)d_in[4];
    float* out = (float*)d_out;
    unsigned short* Wf = (unsigned short*)d_ws;   // 64 KB fragment-ordered bf16 W

    prep_w_kernel<<<128, 256, 0, stream>>>(W, Wf);
    fused_kernel<<<2048, 256, 0, stream>>>(sig, pidx, ck, Wf, bias, out);
}

// Round 2
// 40.346 us; speedup vs baseline: 1.0119x; 1.0119x over previous
//
#include <hip/hip_runtime.h>

// BinaryTreeShConv on MI355X (gfx950).
// out[b,v,i] = relu(bias[i] + sum_{p,c,rn} W[i,c,rn] * K[b,v,p,rn] * sig[b, idx[b,v,p], c])
// B=8 V=4096 P=32 C=32 RN=32 OUT=32, CRN=1024.
//
// R1 changes vs R0 (both passed-correct structure kept):
//  - ck loaded as high-ushort of each f32 (truncate-to-bf16, zero VALU convert)
//  - sig pre-converted to bf16 once (d_ws), gather loads are bare ushorts
//  - T-store rounding cheapened to round-half-up (2 VALU ops)
//
// Stage A (per bv, one wave): T(32c x 32rn) = S^T(32c x 32p) @ K(32p x 32rn)
//   via 2x mfma_f32_32x32x16_bf16. T -> LDS bf16, padded stride 1032.
// Stage B (per block of 16 bv): Out(16bv x 32i) = T(16bv x 1024) @ W^T
//   via mfma_f32_16x16x32_bf16, k-split over 4 waves, LDS reduce.

typedef __attribute__((ext_vector_type(8))) short bf16x8;
typedef __attribute__((ext_vector_type(16))) float f32x16;
typedef __attribute__((ext_vector_type(4))) float f32x4;

__device__ __forceinline__ unsigned short f2bf_rne(float f) {
    union { float f; unsigned int u; } x;
    x.f = f;
    unsigned int u = x.u;
    return (unsigned short)((u + 0x7fffu + ((u >> 16) & 1u)) >> 16);
}
__device__ __forceinline__ unsigned short f2bf_rh(float f) {  // round-half-up
    union { float f; unsigned int u; } x;
    x.f = f;
    return (unsigned short)((x.u + 0x8000u) >> 16);
}

// Wf[pair=2s+t][lane][j] = bf16(W[i=16t+(lane&15)][crn=32s+8*(lane>>4)+j])
// plus sig f32 -> bf16 (RNE), 8 elements/thread.
__global__ __launch_bounds__(256) void prep_kernel(
        const float* __restrict__ W, const float* __restrict__ sig,
        unsigned short* __restrict__ Wf, unsigned short* __restrict__ sigbf) {
    int tid = blockIdx.x * 256 + threadIdx.x;
    if (tid < 32768) {
        int j = tid & 7;
        int l = (tid >> 3) & 63;
        int pair = tid >> 9;                    // s*2 + t
        int s = pair >> 1;
        int t = pair & 1;
        int i = 16 * t + (l & 15);
        int crn = 32 * s + 8 * (l >> 4) + j;    // c = crn>>5, rn = crn&31 (c-major)
        Wf[tid] = f2bf_rne(W[i * 1024 + crn]);
    } else {
        int e = (tid - 32768) * 8;              // sig has 1,048,576 elements
        if (e < 8 * 4096 * 32) {
            f32x4 a = *(const f32x4*)(sig + e);
            f32x4 b = *(const f32x4*)(sig + e + 4);
            bf16x8 v;
            v[0] = (short)f2bf_rne(a[0]); v[1] = (short)f2bf_rne(a[1]);
            v[2] = (short)f2bf_rne(a[2]); v[3] = (short)f2bf_rne(a[3]);
            v[4] = (short)f2bf_rne(b[0]); v[5] = (short)f2bf_rne(b[1]);
            v[6] = (short)f2bf_rne(b[2]); v[7] = (short)f2bf_rne(b[3]);
            *(bf16x8*)(sigbf + e) = v;
        }
    }
}

__global__ __launch_bounds__(256) void fused_kernel(
        const unsigned short* __restrict__ sigbf, const int* __restrict__ pidx,
        const float* __restrict__ ck, const unsigned short* __restrict__ Wf,
        const float* __restrict__ bias, float* __restrict__ out) {
    __shared__ __align__(16) unsigned short T_lds[16 * 1032];  // 33 KB, pad 8 bf16/row
    const int tid = threadIdx.x;
    const int l = tid & 63;
    const int w = tid >> 6;          // wave 0..3
    const int m0 = blockIdx.x * 16;  // first bv of this block (same b for all 16)
    const int b = m0 >> 12;
    const int cc = l & 31;           // stage-A: A-row (c) and B-col (rn)
    const int g = l >> 5;
    const unsigned short* sgb = sigbf + (size_t)b * (4096 * 32);
    const unsigned short* ckh = (const unsigned short*)ck;   // [e*2+1] = bf16-trunc

    // ---- Stage A: wave w computes T for bv_local = 4w .. 4w+3 ----
    for (int q = 0; q < 4; ++q) {
        const int bvl = w * 4 + q;
        const int m = m0 + bvl;
        const int* idxp = pidx + (size_t)m * 32;
        const size_t kbase = (size_t)m * 1024;   // K tile [32p][32rn] f32
        f32x16 acc = {};
        #pragma unroll
        for (int half = 0; half < 2; ++half) {
            bf16x8 af, bfr;
            #pragma unroll
            for (int j = 0; j < 8; ++j) {
                const int p = half * 16 + 8 * g + j;     // k index (consistent A/B)
                const int row = idxp[p];
                af[j]  = (short)sgb[row * 32 + cc];                    // S^T[c][p]
                bfr[j] = (short)ckh[((kbase + p * 32 + cc) << 1) | 1]; // K[p][rn]
            }
            acc = __builtin_amdgcn_mfma_f32_32x32x16_bf16(af, bfr, acc, 0, 0, 0);
        }
        // D map (verified): col=l&31, row=(r&3)+8*(r>>2)+4*(l>>5)
        unsigned short* trow = T_lds + bvl * 1032 + cc + g * 4 * 32;
        #pragma unroll
        for (int r = 0; r < 16; ++r) {
            const int ct = (r & 3) + 8 * (r >> 2);       // + 4g folded into base
            trow[ct * 32] = f2bf_rh(acc[r]);             // T[c][rn] as bf16
        }
    }
    __syncthreads();

    // ---- Stage B: wave w handles k-steps s = 8w..8w+7, both i-tiles ----
    f32x4 acc0 = {}, acc1 = {};
    const int lg = l >> 4;
    const int ln = l & 15;
    #pragma unroll
    for (int si = 0; si < 8; ++si) {
        const int s = 8 * w + si;
        // A-frag: T[bv=ln][crn = 32s + 8*lg + j]  (16B aligned: 1032*2 = 16*129)
        const bf16x8 af = *(const bf16x8*)(T_lds + ln * 1032 + s * 32 + 8 * lg);
        const bf16x8* wrow = (const bf16x8*)(Wf + (size_t)(s * 2) * 512);
        const bf16x8 b0 = wrow[l];        // pair 2s+0, coalesced 16B/lane
        const bf16x8 b1 = wrow[64 + l];   // pair 2s+1
        acc0 = __builtin_amdgcn_mfma_f32_16x16x32_bf16(af, b0, acc0, 0, 0, 0);
        acc1 = __builtin_amdgcn_mfma_f32_16x16x32_bf16(af, b1, acc1, 0, 0, 0);
    }
    __syncthreads();                      // all T reads done; reuse LDS as f32 buf

    float* red = (float*)T_lds;           // 4 waves * 2 tiles * 256 f32 = 8 KB
    {
        f32x4* rp = (f32x4*)(red + w * 512);
        rp[l]      = acc0;                // [w][t=0][l][r]
        rp[64 + l] = acc1;                // [w][t=1][l][r]
    }
    __syncthreads();

    // 512 outputs: o = t*256 + l*4 + r ; D map: row(bv)=(l>>4)*4+r, col(i)=16t+(l&15)
    #pragma unroll
    for (int o0 = 0; o0 < 2; ++o0) {
        const int o = o0 * 256 + tid;
        float sum = red[o] + red[512 + o] + red[1024 + o] + red[1536 + o];
        const int t  = o >> 8;
        const int ll = (o >> 2) & 63;
        const int r  = o & 3;
        const int bv = ((ll >> 4) << 2) + r;
        const int i  = 16 * t + (ll & 15);
        sum += bias[i];
        out[(size_t)(m0 + bv) * 32 + i] = sum > 0.f ? sum : 0.f;
    }
}

extern "C" void kernel_launch(void* const* d_in, const int* in_sizes, int n_in,
                              void* d_out, int out_size, void* d_ws, size_t ws_size,
                              hipStream_t stream) {
    const float* sig  = (const float*)d_in[0];
    const int*   pidx = (const int*)d_in[1];
    const float* ck   = (const float*)d_in[2];
    const float* W    = (const float*)d_in[3];
    const float* bias = (const float*)d_in[4];
    float* out = (float*)d_out;
    unsigned short* Wf    = (unsigned short*)d_ws;       // 64 KB fragment-ordered W
    unsigned short* sigbf = Wf + 32768;                  // 2 MB bf16 signal

    prep_kernel<<<640, 256, 0, stream>>>(W, sig, Wf, sigbf);
    fused_kernel<<<2048, 256, 0, stream>>>(sigbf, pidx, ck, Wf, bias, out);
}